// Round 4
// baseline (204.289 us; speedup 1.0000x reference)
//
#include <hip/hip_runtime.h>
#include <hip/hip_cooperative_groups.h>
#include <math.h>

namespace cg = cooperative_groups;

#define D 64
#define MAXM 20
#define CAP 32   // max groups per user; deg ~ Binomial(40K, 1/20K), P(deg>32) ~ 0
#define WPB 8    // waves per block
#define TPB 512  // threads per block

__global__ __launch_bounds__(TPB) void fused_kernel(
    const int* __restrict__ groups, const int* __restrict__ items,
    const int* __restrict__ membership, const float* __restrict__ member_mask,
    const float* __restrict__ user_emb, const float* __restrict__ item_emb,
    const float* __restrict__ Wk, const float* __restrict__ bk,
    const float* __restrict__ p1w, const float* __restrict__ p1b,
    const float* __restrict__ p2w, const float* __restrict__ p2b,
    float* __restrict__ out,
    float* __restrict__ emb_a, float* __restrict__ emb_b,
    float* __restrict__ nm, int* __restrict__ deg, int* __restrict__ inv,
    int G, int NU, int B, int K) {
  cg::grid_group grid = cg::this_grid();
  const int w    = threadIdx.x >> 6;
  const int lane = threadIdx.x & 63;
  const int gw   = blockIdx.x * WPB + w;     // one group per wave
  const int nthreads = gridDim.x * TPB;
  const int nwaves   = gridDim.x * WPB;

  __shared__ int   mem_s[WPB][MAXM];
  __shared__ float wgt_s[WPB][MAXM];
  __shared__ float e_s[WPB][D];
  __shared__ float ms_s[WPB][D];
  int*   mem   = mem_s[w];
  float* wgt   = wgt_s[w];
  float* e_sh  = e_s[w];
  float* ms_sh = ms_s[w];

  // ---- phase 0: zero deg (doubles as inv-fill cursor) ----
  for (int i = blockIdx.x * TPB + threadIdx.x; i < NU; i += nthreads)
    deg[i] = 0;
  grid.sync();

  // ---- phase A: masked-mean init + dedup + deg/inv build ----
  unsigned long long ufmask = 0ull;
  float ucnt_f = 0.f;
  if (gw < G && lane < MAXM) {
    mem[lane] = membership[gw * MAXM + lane];
    wgt[lane] = expf(member_mask[gw * MAXM + lane]);
  }
  __syncthreads();
  if (gw < G) {
    float acc = 0.f, wsum = 0.f;
#pragma unroll
    for (int m = 0; m < MAXM; ++m) {
      acc  += wgt[m] * user_emb[(long)mem[m] * D + lane];
      wsum += wgt[m];
    }
    emb_a[(long)gw * D + lane] = acc / wsum;

    bool uniq = false;
    if (lane < MAXM) {
      const int u = mem[lane];
      uniq = true;
      for (int m = 0; m < lane; ++m)
        if (mem[m] == u) uniq = false;
    }
    ufmask = __ballot(uniq);
    ucnt_f = (float)__popcll(ufmask);
    if (uniq) {
      const int u = mem[lane];
      const int pos = atomicAdd(&deg[u], 1);
      if (pos < CAP) inv[(long)u * CAP + pos] = gw;
    }
  }
  grid.sync();

  // ---- phases B: K graph-conv updates (gather-only, no atomics) ----
  float* cur = emb_a;
  float* nxt = emb_b;
  for (int k = 0; k < K; ++k) {
    float ein = 0.f;
    if (gw < G) ein = cur[(long)gw * D + lane];
    e_sh[lane] = ein;
    __syncthreads();

    float msv = 0.f;
    if (gw < G) {
      float ng = 0.f, nmv = 0.f;
#pragma unroll
      for (int m = 0; m < MAXM; ++m) {
        if (!((ufmask >> m) & 1ull)) continue;
        const int u = mem[m];
        const int d = deg[u];
        if (k == 0) nmv += (float)(d - 1) * user_emb[(long)u * D + lane];
        const int dd = (d < CAP) ? d : CAP;
        const long base = (long)u * CAP;
        for (int i = 0; i < dd; ++i)
          ng += cur[(long)inv[base + i] * D + lane];
      }
      if (k == 0) nm[(long)gw * D + lane] = nmv;
      else        nmv = nm[(long)gw * D + lane];
      msv = ng - ucnt_f * ein + nmv;
    }
    ms_sh[lane] = msv;
    __syncthreads();

    if (gw < G) {
      const float* Wrow = Wk + ((long)k * D + lane) * (2 * D);
      float o = bk[k * D + lane];
#pragma unroll
      for (int j = 0; j < D; ++j)
        o += e_sh[j] * Wrow[j] + ms_sh[j] * Wrow[D + j];
      float ss = o * o;
#pragma unroll
      for (int sh = 32; sh; sh >>= 1) ss += __shfl_xor(ss, sh);
      o *= 1.f / fmaxf(sqrtf(ss), 1e-12f);
      nxt[(long)gw * D + lane] = o;
    }
    float* tmp = cur; cur = nxt; nxt = tmp;
    grid.sync();
  }

  // ---- phase D: prediction head, one wave per sample, grid-stride ----
  for (int s = gw; s < B; s += nwaves) {
    const int g  = groups[s];
    const int it = items[s];
    const float x = cur[(long)g * D + lane] * item_emb[(long)it * D + lane];
    float acc2 = p2b[0];
#pragma unroll
    for (int j = 0; j < 16; ++j) {
      float p = x * p1w[j * D + lane];
#pragma unroll
      for (int off = 32; off; off >>= 1) p += __shfl_xor(p, off);
      const float h = fmaxf(p + p1b[j], 0.f);
      acc2 += h * p2w[j];
    }
    if (lane == 0) out[s] = 1.f / (1.f + expf(-acc2));
  }
}

extern "C" void kernel_launch(void* const* d_in, const int* in_sizes, int n_in,
                              void* d_out, int out_size, void* d_ws, size_t ws_size,
                              hipStream_t stream) {
  const int*   groups      = (const int*)d_in[0];
  const int*   items       = (const int*)d_in[1];
  const int*   membership  = (const int*)d_in[2];
  const float* member_mask = (const float*)d_in[3];
  // d_in[4] hyper_graph: not needed (binary incidence == membership lists)
  const float* user_emb    = (const float*)d_in[5];
  const float* item_emb    = (const float*)d_in[6];
  const float* Wk          = (const float*)d_in[7];
  const float* bk          = (const float*)d_in[8];
  const float* p1w         = (const float*)d_in[9];
  const float* p1b         = (const float*)d_in[10];
  const float* p2w         = (const float*)d_in[11];
  const float* p2b         = (const float*)d_in[12];
  float* out = (float*)d_out;

  int B  = in_sizes[0];
  int G  = in_sizes[2] / MAXM;
  int NU = in_sizes[5] / D;
  int K  = in_sizes[7] / (D * 2 * D);

  char* ws = (char*)d_ws;
  float* emb_a = (float*)ws; ws += (size_t)G * D * 4;
  float* emb_b = (float*)ws; ws += (size_t)G * D * 4;
  float* nm    = (float*)ws; ws += (size_t)G * D * 4;
  int*   deg   = (int*)ws;   ws += (size_t)NU * 4;
  int*   inv   = (int*)ws;   ws += (size_t)NU * CAP * 4;

  const int nblk = (G + WPB - 1) / WPB;  // 250 blocks <= 256 CUs: co-resident

  void* args[] = {
    (void*)&groups, (void*)&items, (void*)&membership, (void*)&member_mask,
    (void*)&user_emb, (void*)&item_emb, (void*)&Wk, (void*)&bk,
    (void*)&p1w, (void*)&p1b, (void*)&p2w, (void*)&p2b,
    (void*)&out, (void*)&emb_a, (void*)&emb_b, (void*)&nm,
    (void*)&deg, (void*)&inv,
    (void*)&G, (void*)&NU, (void*)&B, (void*)&K
  };
  hipLaunchCooperativeKernel((const void*)fused_kernel, dim3(nblk), dim3(TPB),
                             args, 0, stream);
}

// Round 5
// 60.116 us; speedup vs baseline: 3.3982x; 3.3982x over previous
//
#include <hip/hip_runtime.h>
#include <math.h>

#define D 64
#define MAXM 20
#define CAP 32    // max groups per user (deg ~ Poisson(2); P(>32) ~ 1e-27)
#define CAPS 64   // max samples per group (count ~ Poisson(4.1); P(>64) ~ 0)

// Zero deg[NU] and scnt[G] (allocated contiguously: n = NU + G).
__global__ void zero_kernel(int* __restrict__ p, int n) {
  const int i = blockIdx.x * blockDim.x + threadIdx.x;
  if (i < n) p[i] = 0;
}

// One wave per group: masked-mean emb0, dedup bitmask, deg/inv build.
// Epilogue: grid-stride build of group->samples index (scnt/sidx).
__global__ void init_kernel(const int* __restrict__ membership,
                            const float* __restrict__ member_mask,
                            const float* __restrict__ user_emb,
                            const int* __restrict__ groups,
                            float* __restrict__ emb0,
                            unsigned int* __restrict__ ufm,
                            int* __restrict__ deg, int* __restrict__ inv,
                            int* __restrict__ scnt, int* __restrict__ sidx,
                            int G, int B) {
  const int g = blockIdx.x;
  const int lane = threadIdx.x;  // 64 threads = 1 wave; lane == emb dim
  __shared__ int   mem[MAXM];
  __shared__ float wgt[MAXM];
  if (lane < MAXM) {
    mem[lane] = membership[g * MAXM + lane];
    wgt[lane] = expf(member_mask[g * MAXM + lane]);
  }
  __syncthreads();

  float acc = 0.f, wsum = 0.f;
#pragma unroll
  for (int m = 0; m < MAXM; ++m) {
    acc  += wgt[m] * user_emb[(long)mem[m] * D + lane];
    wsum += wgt[m];
  }
  emb0[(long)g * D + lane] = acc / wsum;

  bool uniq = false;
  if (lane < MAXM) {
    const int u = mem[lane];
    uniq = true;
    for (int m = 0; m < lane; ++m)
      if (mem[m] == u) uniq = false;
  }
  const unsigned long long bal = __ballot(uniq);
  if (lane == 0) ufm[g] = (unsigned int)bal;
  if (uniq) {
    const int u = mem[lane];
    const int pos = atomicAdd(&deg[u], 1);
    if (pos < CAP) inv[(long)u * CAP + pos] = g;
  }

  // group->samples index (covers B since G*64 >= B; grid-stride for safety)
  for (int s = g * 64 + lane; s < B; s += G * 64) {
    const int gg = groups[s];
    const int pos = atomicAdd(&scnt[gg], 1);
    if (pos < CAPS) sidx[gg * CAPS + pos] = s;
  }
}

// Shared body: compute this group's updated, l2-normalized embedding o.
// ng via inverse-index gather (no atomics); nm computed at k==0 else read.
__device__ __forceinline__ float update_core(
    const int* __restrict__ membership, const unsigned int* __restrict__ ufm,
    const int* __restrict__ deg, const int* __restrict__ inv,
    const float* __restrict__ user_emb, float* __restrict__ nm, int compute_nm,
    const float* __restrict__ Wk, const float* __restrict__ bk, int k,
    const float* __restrict__ cur, int g, int lane,
    int* mem, float* coef, float* e_sh, float* ms_sh, int* nbr) {
  if (lane < MAXM) mem[lane] = membership[g * MAXM + lane];
  __syncthreads();
  const unsigned int um = ufm[g];
  const float ucnt = (float)__popc(um);
  const float ein = cur[(long)g * D + lane];
  e_sh[lane] = ein;

  // build neighbor list in LDS (prefix-scan of per-member degrees)
  int d = 0, u = 0;
  if (lane < MAXM && ((um >> lane) & 1u)) { u = mem[lane]; d = deg[u]; }
  if (compute_nm && lane < MAXM)
    coef[lane] = ((um >> lane) & 1u) ? (float)(d - 1) : 0.f;
  const int dc = d < CAP ? d : CAP;
  int incl = dc;
#pragma unroll
  for (int off = 1; off < 64; off <<= 1) {
    const int v = __shfl_up(incl, off);
    if (lane >= off) incl += v;
  }
  const int total = __shfl(incl, 63);
  const int base = incl - dc;
  for (int i = 0; i < dc; ++i) nbr[base + i] = inv[(long)u * CAP + i];
  __syncthreads();

  // gather neighbor embeddings, 4-wide unrolled (independent loads in flight)
  float ng = 0.f;
  int i = 0;
  for (; i + 4 <= total; i += 4) {
    const int n0 = nbr[i], n1 = nbr[i + 1], n2 = nbr[i + 2], n3 = nbr[i + 3];
    const float a0 = cur[(long)n0 * D + lane];
    const float a1 = cur[(long)n1 * D + lane];
    const float a2 = cur[(long)n2 * D + lane];
    const float a3 = cur[(long)n3 * D + lane];
    ng += (a0 + a1) + (a2 + a3);
  }
  for (; i < total; ++i) ng += cur[(long)nbr[i] * D + lane];

  float nmv;
  if (compute_nm) {
    nmv = 0.f;
#pragma unroll
    for (int m = 0; m < MAXM; ++m)
      nmv += coef[m] * user_emb[(long)mem[m] * D + lane];
    nm[(long)g * D + lane] = nmv;
  } else {
    nmv = nm[(long)g * D + lane];
  }
  ms_sh[lane] = ng - ucnt * ein + nmv;
  __syncthreads();

  const float* Wrow = Wk + ((long)k * D + lane) * (2 * D);
  float o = bk[k * D + lane];
#pragma unroll
  for (int j = 0; j < D; ++j)
    o += e_sh[j] * Wrow[j] + ms_sh[j] * Wrow[D + j];
  float ss = o * o;
#pragma unroll
  for (int sh = 32; sh; sh >>= 1) ss += __shfl_xor(ss, sh);
  return o * (1.f / fmaxf(sqrtf(ss), 1e-12f));
}

// Middle iteration: writes updated embedding.
__global__ void upd_kernel(const int* __restrict__ membership,
                           const unsigned int* __restrict__ ufm,
                           const int* __restrict__ deg,
                           const int* __restrict__ inv,
                           const float* __restrict__ user_emb,
                           float* __restrict__ nm, int compute_nm,
                           const float* __restrict__ Wk,
                           const float* __restrict__ bk, int k,
                           const float* __restrict__ cur,
                           float* __restrict__ nxt) {
  const int g = blockIdx.x, lane = threadIdx.x;
  __shared__ int   mem[MAXM];
  __shared__ float coef[MAXM];
  __shared__ float e_sh[D], ms_sh[D];
  __shared__ int   nbr[MAXM * CAP];
  const float o = update_core(membership, ufm, deg, inv, user_emb, nm,
                              compute_nm, Wk, bk, k, cur, g, lane,
                              mem, coef, e_sh, ms_sh, nbr);
  nxt[(long)g * D + lane] = o;
}

// Last iteration fused with the prediction head over this group's samples.
__global__ void upd_head_kernel(const int* __restrict__ membership,
                                const unsigned int* __restrict__ ufm,
                                const int* __restrict__ deg,
                                const int* __restrict__ inv,
                                const float* __restrict__ user_emb,
                                float* __restrict__ nm, int compute_nm,
                                const float* __restrict__ Wk,
                                const float* __restrict__ bk, int k,
                                const float* __restrict__ cur,
                                const int* __restrict__ scnt,
                                const int* __restrict__ sidx,
                                const int* __restrict__ items,
                                const float* __restrict__ item_emb,
                                const float* __restrict__ p1w,
                                const float* __restrict__ p1b,
                                const float* __restrict__ p2w,
                                const float* __restrict__ p2b,
                                float* __restrict__ out) {
  const int g = blockIdx.x, lane = threadIdx.x;
  __shared__ int   mem[MAXM];
  __shared__ float coef[MAXM];
  __shared__ float e_sh[D], ms_sh[D];
  __shared__ int   nbr[MAXM * CAP];
  const float o = update_core(membership, ufm, deg, inv, user_emb, nm,
                              compute_nm, Wk, bk, k, cur, g, lane,
                              mem, coef, e_sh, ms_sh, nbr);

  const int ns0 = scnt[g];
  const int ns = ns0 < CAPS ? ns0 : CAPS;
  if (ns > 0) {
    float p1r[16], p1br[16], p2wr[16];
#pragma unroll
    for (int j = 0; j < 16; ++j) {
      p1r[j]  = p1w[j * D + lane];
      p1br[j] = p1b[j];
      p2wr[j] = p2w[j];
    }
    const float p2b0 = p2b[0];
    for (int si = 0; si < ns; ++si) {
      const int s  = sidx[g * CAPS + si];
      const int it = items[s];
      const float x = o * item_emb[(long)it * D + lane];
      float pv[16];
#pragma unroll
      for (int j = 0; j < 16; ++j) pv[j] = x * p1r[j];
#pragma unroll
      for (int off = 32; off; off >>= 1) {
#pragma unroll
        for (int j = 0; j < 16; ++j) pv[j] += __shfl_xor(pv[j], off);
      }
      float acc2 = p2b0;
#pragma unroll
      for (int j = 0; j < 16; ++j)
        acc2 += fmaxf(pv[j] + p1br[j], 0.f) * p2wr[j];
      if (lane == 0) out[s] = 1.f / (1.f + expf(-acc2));
    }
  }
}

extern "C" void kernel_launch(void* const* d_in, const int* in_sizes, int n_in,
                              void* d_out, int out_size, void* d_ws, size_t ws_size,
                              hipStream_t stream) {
  const int*   groups      = (const int*)d_in[0];
  const int*   items       = (const int*)d_in[1];
  const int*   membership  = (const int*)d_in[2];
  const float* member_mask = (const float*)d_in[3];
  // d_in[4] hyper_graph: not needed (binary incidence == membership lists)
  const float* user_emb    = (const float*)d_in[5];
  const float* item_emb    = (const float*)d_in[6];
  const float* Wk          = (const float*)d_in[7];
  const float* bk          = (const float*)d_in[8];
  const float* p1w         = (const float*)d_in[9];
  const float* p1b         = (const float*)d_in[10];
  const float* p2w         = (const float*)d_in[11];
  const float* p2b         = (const float*)d_in[12];
  float* out = (float*)d_out;

  const int B  = in_sizes[0];
  const int G  = in_sizes[2] / MAXM;
  const int NU = in_sizes[5] / D;
  const int K  = in_sizes[7] / (D * 2 * D);

  char* ws = (char*)d_ws;
  float*        emb_a = (float*)ws;        ws += (size_t)G * D * 4;
  float*        emb_b = (float*)ws;        ws += (size_t)G * D * 4;
  float*        nm    = (float*)ws;        ws += (size_t)G * D * 4;
  int*          deg   = (int*)ws;          ws += (size_t)NU * 4;   // contiguous
  int*          scnt  = (int*)ws;          ws += (size_t)G * 4;    // with deg
  int*          inv   = (int*)ws;          ws += (size_t)NU * CAP * 4;
  int*          sidx  = (int*)ws;          ws += (size_t)G * CAPS * 4;
  unsigned int* ufm   = (unsigned int*)ws; ws += (size_t)G * 4;

  zero_kernel<<<(NU + G + 255) / 256, 256, 0, stream>>>(deg, NU + G);
  init_kernel<<<G, 64, 0, stream>>>(membership, member_mask, user_emb, groups,
                                    emb_a, ufm, deg, inv, scnt, sidx, G, B);

  float* cur = emb_a;
  float* nxt = emb_b;
  for (int k = 0; k < K - 1; ++k) {
    upd_kernel<<<G, 64, 0, stream>>>(membership, ufm, deg, inv, user_emb,
                                     nm, (k == 0) ? 1 : 0, Wk, bk, k, cur, nxt);
    float* tmp = cur; cur = nxt; nxt = tmp;
  }
  upd_head_kernel<<<G, 64, 0, stream>>>(
      membership, ufm, deg, inv, user_emb, nm, (K == 1) ? 1 : 0, Wk, bk, K - 1,
      cur, scnt, sidx, items, item_emb, p1w, p1b, p2w, p2b, out);
}

// Round 6
// 58.573 us; speedup vs baseline: 3.4878x; 1.0263x over previous
//
#include <hip/hip_runtime.h>
#include <math.h>

#define D 64
#define MAXM 20
#define CAP 32    // max groups per user (deg ~ Poisson(2); P(>32) ~ 1e-27)
#define CAPS 64   // max samples per group (count ~ Poisson(4.1); P(>64) ~ 0)
#define WPB 4     // waves (groups) per block
#define TPB 256

#define XOR_COMBINE4(v)                                        \
  do {                                                         \
    v.x += __shfl_xor(v.x, 16); v.x += __shfl_xor(v.x, 32);    \
    v.y += __shfl_xor(v.y, 16); v.y += __shfl_xor(v.y, 32);    \
    v.z += __shfl_xor(v.z, 16); v.z += __shfl_xor(v.z, 32);    \
    v.w += __shfl_xor(v.w, 16); v.w += __shfl_xor(v.w, 32);    \
  } while (0)

// One wave per group: masked-mean emb0 (float4 4-row gathers), dedup bitmask,
// deg/inv build. Epilogue: group->samples index (scnt/sidx).
__global__ __launch_bounds__(TPB) void init_kernel(
    const int* __restrict__ membership, const float* __restrict__ member_mask,
    const float* __restrict__ user_emb, const int* __restrict__ groups,
    float* __restrict__ emb0, unsigned int* __restrict__ ufm,
    int* __restrict__ deg, int* __restrict__ inv,
    int* __restrict__ scnt, int* __restrict__ sidx, int G, int B) {
  const int w    = threadIdx.x >> 6;
  const int lane = threadIdx.x & 63;
  const int g    = blockIdx.x * WPB + w;
  const int sub  = lane >> 4, q = lane & 15;
  __shared__ int   mem_s[WPB][MAXM];
  __shared__ float wgt_s[WPB][MAXM];
  int*   mem = mem_s[w];
  float* wgt = wgt_s[w];
  if (g < G && lane < MAXM) {
    mem[lane] = membership[g * MAXM + lane];
    wgt[lane] = expf(member_mask[g * MAXM + lane]);
  }
  __syncthreads();
  if (g < G) {
    float wsum = 0.f;
#pragma unroll
    for (int m = 0; m < MAXM; ++m) wsum += wgt[m];
    float4 acc = make_float4(0.f, 0.f, 0.f, 0.f);
#pragma unroll
    for (int it = 0; it < MAXM / 4; ++it) {   // 4 rows per instruction
      const int m = it * 4 + sub;
      const float c = wgt[m];
      const float4 v = *(const float4*)(user_emb + (long)mem[m] * D + q * 4);
      acc.x += c * v.x; acc.y += c * v.y; acc.z += c * v.z; acc.w += c * v.w;
    }
    XOR_COMBINE4(acc);
    if (lane < 16) {
      const float iw = 1.f / wsum;
      float4 r = make_float4(acc.x * iw, acc.y * iw, acc.z * iw, acc.w * iw);
      ((float4*)(emb0 + (long)g * D))[q] = r;
    }
    bool uniq = false;
    if (lane < MAXM) {
      const int u = mem[lane];
      uniq = true;
      for (int m = 0; m < lane; ++m)
        if (mem[m] == u) uniq = false;
    }
    const unsigned long long bal = __ballot(uniq);
    if (lane == 0) ufm[g] = (unsigned int)bal;
    if (uniq) {
      const int u = mem[lane];
      const int pos = atomicAdd(&deg[u], 1);
      if (pos < CAP) inv[(long)u * CAP + pos] = g;
    }
  }
  // group->samples index
  const int nthreads = gridDim.x * TPB;
  for (int s = blockIdx.x * TPB + threadIdx.x; s < B; s += nthreads) {
    const int gg = groups[s];
    const int pos = atomicAdd(&scnt[gg], 1);
    if (pos < CAPS) sidx[gg * CAPS + pos] = s;
  }
}

// Shared body: updated, l2-normalized embedding of group g.
// ng via inverse-index gather, 4 rows per float4 instruction; pad rows = g,
// folded into the -(ucnt+padc)*e term. nm computed at k==0, reread after.
__device__ __forceinline__ float update_core(
    const int* __restrict__ membership, const unsigned int* __restrict__ ufm,
    const int* __restrict__ deg, const int* __restrict__ inv,
    const float* __restrict__ user_emb, float* __restrict__ nm, int compute_nm,
    const float* __restrict__ Wk, const float* __restrict__ bk, int k,
    const float* __restrict__ cur, int g, int lane,
    int* mem, float* coef, float* e_sh, float* ms_sh, int* nbr) {
  const int sub = lane >> 4, q = lane & 15;
  if (lane < MAXM) mem[lane] = membership[g * MAXM + lane];
  const unsigned int um = ufm[g];
  const float ein = cur[(long)g * D + lane];
  e_sh[lane] = ein;

  int d = 0, u = 0;
  const bool uq = (lane < MAXM) && ((um >> lane) & 1u);
  if (uq) { u = mem[lane]; d = deg[u]; }
  if (lane < MAXM) coef[lane] = uq ? (float)(d - 1) : 0.f;
  const int dc = d < CAP ? d : CAP;
  int incl = dc;
#pragma unroll
  for (int off = 1; off < 64; off <<= 1) {
    const int v = __shfl_up(incl, off);
    if (lane >= off) incl += v;
  }
  const int total = __shfl(incl, 63);
  const int base = incl - dc;
  for (int i = 0; i < dc; ++i) nbr[base + i] = inv[(long)u * CAP + i];
  const int padc = (4 - (total & 3)) & 3;
  if (lane < padc) nbr[total + lane] = g;   // pad rows: subtracted via alpha
  __syncthreads();

  const int T4 = total + padc;
  float4 ng4 = make_float4(0.f, 0.f, 0.f, 0.f);
  for (int i = 0; i < T4; i += 4) {
    const int row = nbr[i + sub];
    const float4 v = *(const float4*)(cur + (long)row * D + q * 4);
    ng4.x += v.x; ng4.y += v.y; ng4.z += v.z; ng4.w += v.w;
  }
  XOR_COMBINE4(ng4);

  float4 nm4 = make_float4(0.f, 0.f, 0.f, 0.f);
  if (compute_nm) {
#pragma unroll
    for (int it = 0; it < MAXM / 4; ++it) {
      const int m = it * 4 + sub;
      const float c = coef[m];
      const float4 v = *(const float4*)(user_emb + (long)mem[m] * D + q * 4);
      nm4.x += c * v.x; nm4.y += c * v.y; nm4.z += c * v.z; nm4.w += c * v.w;
    }
    XOR_COMBINE4(nm4);
    if (lane < 16) ((float4*)(nm + (long)g * D))[q] = nm4;
  }
  if (lane < 16) {
    const float4 nmv4 =
        compute_nm ? nm4 : ((const float4*)(nm + (long)g * D))[q];
    const float alpha = (float)__popc(um) + (float)padc;
    const float4 e4 = ((const float4*)e_sh)[q];
    float4 ms4;
    ms4.x = ng4.x + nmv4.x - alpha * e4.x;
    ms4.y = ng4.y + nmv4.y - alpha * e4.y;
    ms4.z = ng4.z + nmv4.z - alpha * e4.z;
    ms4.w = ng4.w + nmv4.w - alpha * e4.w;
    ((float4*)ms_sh)[q] = ms4;
  }
  __syncthreads();

  const float4* W4 = (const float4*)(Wk + ((long)k * D + lane) * (2 * D));
  const float4* e4p = (const float4*)e_sh;
  const float4* m4p = (const float4*)ms_sh;
  float o = bk[k * D + lane];
#pragma unroll
  for (int j = 0; j < 16; ++j) {
    const float4 a = e4p[j], wv = W4[j];
    o += a.x * wv.x + a.y * wv.y + a.z * wv.z + a.w * wv.w;
  }
#pragma unroll
  for (int j = 0; j < 16; ++j) {
    const float4 a = m4p[j], wv = W4[16 + j];
    o += a.x * wv.x + a.y * wv.y + a.z * wv.z + a.w * wv.w;
  }
  float ss = o * o;
#pragma unroll
  for (int sh = 32; sh; sh >>= 1) ss += __shfl_xor(ss, sh);
  return o * (1.f / fmaxf(sqrtf(ss), 1e-12f));
}

// Middle iteration: writes updated embedding.
__global__ __launch_bounds__(TPB) void upd_kernel(
    const int* __restrict__ membership, const unsigned int* __restrict__ ufm,
    const int* __restrict__ deg, const int* __restrict__ inv,
    const float* __restrict__ user_emb, float* __restrict__ nm, int compute_nm,
    const float* __restrict__ Wk, const float* __restrict__ bk, int k,
    const float* __restrict__ cur, float* __restrict__ nxt, int G) {
  const int w = threadIdx.x >> 6, lane = threadIdx.x & 63;
  const int g0 = blockIdx.x * WPB + w;
  const int g = g0 < G ? g0 : G - 1;
  __shared__ int   mem_s[WPB][MAXM];
  __shared__ float coef_s[WPB][MAXM];
  __shared__ float e_s[WPB][D], ms_s[WPB][D];
  __shared__ int   nbr_s[WPB][MAXM * CAP + 4];
  const float o = update_core(membership, ufm, deg, inv, user_emb, nm,
                              compute_nm, Wk, bk, k, cur, g, lane,
                              mem_s[w], coef_s[w], e_s[w], ms_s[w], nbr_s[w]);
  if (g0 < G) nxt[(long)g0 * D + lane] = o;
}

// Last iteration fused with the prediction head; the block's 4 waves pool
// their groups' samples to cut straggler tails.
__global__ __launch_bounds__(TPB) void upd_head_kernel(
    const int* __restrict__ membership, const unsigned int* __restrict__ ufm,
    const int* __restrict__ deg, const int* __restrict__ inv,
    const float* __restrict__ user_emb, float* __restrict__ nm, int compute_nm,
    const float* __restrict__ Wk, const float* __restrict__ bk, int k,
    const float* __restrict__ cur,
    const int* __restrict__ scnt, const int* __restrict__ sidx,
    const int* __restrict__ items, const float* __restrict__ item_emb,
    const float* __restrict__ p1w, const float* __restrict__ p1b,
    const float* __restrict__ p2w, const float* __restrict__ p2b,
    float* __restrict__ out, int G) {
  const int w = threadIdx.x >> 6, lane = threadIdx.x & 63;
  const int g0 = blockIdx.x * WPB + w;
  const int g = g0 < G ? g0 : G - 1;
  __shared__ int   mem_s[WPB][MAXM];
  __shared__ float coef_s[WPB][MAXM];
  __shared__ float e_s[WPB][D], ms_s[WPB][D];
  __shared__ int   nbr_s[WPB][MAXM * CAP + 4];
  const float o = update_core(membership, ufm, deg, inv, user_emb, nm,
                              compute_nm, Wk, bk, k, cur, g, lane,
                              mem_s[w], coef_s[w], e_s[w], ms_s[w], nbr_s[w]);

  __shared__ float o_sh[WPB][D];
  __shared__ int   slist[WPB * CAPS];
  __shared__ unsigned char sgw[WPB * CAPS];
  __shared__ int   soff[WPB + 1];
  __shared__ int   scnt_sh[WPB];
  o_sh[w][lane] = o;
  if (lane == 0) scnt_sh[w] = (g0 < G) ? min(scnt[g0], CAPS) : 0;
  __syncthreads();
  if (threadIdx.x == 0) {
    soff[0] = 0;
    for (int i = 0; i < WPB; ++i) soff[i + 1] = soff[i] + scnt_sh[i];
  }
  __syncthreads();
  const int my = scnt_sh[w];
  for (int i = lane; i < my; i += 64) {
    slist[soff[w] + i] = sidx[g0 * CAPS + i];
    sgw[soff[w] + i] = (unsigned char)w;
  }
  __syncthreads();
  const int T = soff[WPB];
  if (T == 0) return;
  float p1r[16], p1br[16], p2wr[16];
#pragma unroll
  for (int j = 0; j < 16; ++j) {
    p1r[j]  = p1w[j * D + lane];
    p1br[j] = p1b[j];
    p2wr[j] = p2w[j];
  }
  const float p2b0 = p2b[0];
  for (int e = w; e < T; e += WPB) {
    const int s = slist[e];
    const int gw2 = sgw[e];
    const float x = o_sh[gw2][lane] * item_emb[(long)items[s] * D + lane];
    float pv[16];
#pragma unroll
    for (int j = 0; j < 16; ++j) pv[j] = x * p1r[j];
#pragma unroll
    for (int off = 32; off; off >>= 1) {
#pragma unroll
      for (int j = 0; j < 16; ++j) pv[j] += __shfl_xor(pv[j], off);
    }
    float acc2 = p2b0;
#pragma unroll
    for (int j = 0; j < 16; ++j)
      acc2 += fmaxf(pv[j] + p1br[j], 0.f) * p2wr[j];
    if (lane == 0) out[s] = 1.f / (1.f + expf(-acc2));
  }
}

extern "C" void kernel_launch(void* const* d_in, const int* in_sizes, int n_in,
                              void* d_out, int out_size, void* d_ws, size_t ws_size,
                              hipStream_t stream) {
  const int*   groups      = (const int*)d_in[0];
  const int*   items       = (const int*)d_in[1];
  const int*   membership  = (const int*)d_in[2];
  const float* member_mask = (const float*)d_in[3];
  // d_in[4] hyper_graph: not needed (binary incidence == membership lists)
  const float* user_emb    = (const float*)d_in[5];
  const float* item_emb    = (const float*)d_in[6];
  const float* Wk          = (const float*)d_in[7];
  const float* bk          = (const float*)d_in[8];
  const float* p1w         = (const float*)d_in[9];
  const float* p1b         = (const float*)d_in[10];
  const float* p2w         = (const float*)d_in[11];
  const float* p2b         = (const float*)d_in[12];
  float* out = (float*)d_out;

  const int B  = in_sizes[0];
  const int G  = in_sizes[2] / MAXM;
  const int NU = in_sizes[5] / D;
  const int K  = in_sizes[7] / (D * 2 * D);

  char* ws = (char*)d_ws;
  float*        emb_a = (float*)ws;        ws += (size_t)G * D * 4;
  float*        emb_b = (float*)ws;        ws += (size_t)G * D * 4;
  float*        nm    = (float*)ws;        ws += (size_t)G * D * 4;
  int*          deg   = (int*)ws;          ws += (size_t)NU * 4;   // contiguous
  int*          scnt  = (int*)ws;          ws += (size_t)G * 4;    // with deg
  int*          inv   = (int*)ws;          ws += (size_t)NU * CAP * 4;
  int*          sidx  = (int*)ws;          ws += (size_t)G * CAPS * 4;
  unsigned int* ufm   = (unsigned int*)ws; ws += (size_t)G * 4;

  const int nblk = (G + WPB - 1) / WPB;

  hipMemsetAsync(deg, 0, (size_t)(NU + G) * 4, stream);  // deg + scnt
  init_kernel<<<nblk, TPB, 0, stream>>>(membership, member_mask, user_emb,
                                        groups, emb_a, ufm, deg, inv,
                                        scnt, sidx, G, B);

  float* cur = emb_a;
  float* nxt = emb_b;
  for (int k = 0; k < K - 1; ++k) {
    upd_kernel<<<nblk, TPB, 0, stream>>>(membership, ufm, deg, inv, user_emb,
                                         nm, (k == 0) ? 1 : 0, Wk, bk, k,
                                         cur, nxt, G);
    float* tmp = cur; cur = nxt; nxt = tmp;
  }
  upd_head_kernel<<<nblk, TPB, 0, stream>>>(
      membership, ufm, deg, inv, user_emb, nm, (K == 1) ? 1 : 0, Wk, bk, K - 1,
      cur, scnt, sidx, items, item_emb, p1w, p1b, p2w, p2b, out, G);
}

// Round 7
// 57.089 us; speedup vs baseline: 3.5784x; 1.0260x over previous
//
#include <hip/hip_runtime.h>
#include <math.h>

#define D 64
#define MAXM 20
#define CAP 32    // max groups per user (deg ~ Poisson(2); P(>32) ~ 1e-27)
#define CAPS 64   // max samples per group (count ~ Poisson(4.1); P(>64) ~ 0)
#define WPB 8     // waves (groups) per block -> 250 blocks, 1 per CU
#define TPB 512

#define XOR_COMBINE4(v)                                        \
  do {                                                         \
    v.x += __shfl_xor(v.x, 16); v.x += __shfl_xor(v.x, 32);    \
    v.y += __shfl_xor(v.y, 16); v.y += __shfl_xor(v.y, 32);    \
    v.z += __shfl_xor(v.z, 16); v.z += __shfl_xor(v.z, 32);    \
    v.w += __shfl_xor(v.w, 16); v.w += __shfl_xor(v.w, 32);    \
  } while (0)

// One wave per group: masked-mean emb0 (float4 4-row gathers), dedup bitmask,
// deg/inv build. Epilogue: group->samples index (scnt/sidx).
// NOTE: mem/wgt are wave-private LDS; no cross-wave barrier needed (same-wave
// LDS RAW is ordered by compiler-inserted s_waitcnt lgkmcnt).
__global__ __launch_bounds__(TPB) void init_kernel(
    const int* __restrict__ membership, const float* __restrict__ member_mask,
    const float* __restrict__ user_emb, const int* __restrict__ groups,
    float* __restrict__ emb0, unsigned int* __restrict__ ufm,
    int* __restrict__ deg, int* __restrict__ inv,
    int* __restrict__ scnt, int* __restrict__ sidx, int G, int B) {
  const int w    = threadIdx.x >> 6;
  const int lane = threadIdx.x & 63;
  const int g    = blockIdx.x * WPB + w;
  const int sub  = lane >> 4, q = lane & 15;
  __shared__ int   mem_s[WPB][MAXM];
  __shared__ float wgt_s[WPB][MAXM];
  int*   mem = mem_s[w];
  float* wgt = wgt_s[w];
  if (g < G) {
    if (lane < MAXM) {
      mem[lane] = membership[g * MAXM + lane];
      wgt[lane] = expf(member_mask[g * MAXM + lane]);
    }
    float wsum = 0.f;
#pragma unroll
    for (int m = 0; m < MAXM; ++m) wsum += wgt[m];
    float4 acc = make_float4(0.f, 0.f, 0.f, 0.f);
#pragma unroll
    for (int it = 0; it < MAXM / 4; ++it) {   // 4 rows per instruction
      const int m = it * 4 + sub;
      const float c = wgt[m];
      const float4 v = *(const float4*)(user_emb + (long)mem[m] * D + q * 4);
      acc.x += c * v.x; acc.y += c * v.y; acc.z += c * v.z; acc.w += c * v.w;
    }
    XOR_COMBINE4(acc);
    if (lane < 16) {
      const float iw = 1.f / wsum;
      float4 r = make_float4(acc.x * iw, acc.y * iw, acc.z * iw, acc.w * iw);
      ((float4*)(emb0 + (long)g * D))[q] = r;
    }
    bool uniq = false;
    if (lane < MAXM) {
      const int u = mem[lane];
      uniq = true;
      for (int m = 0; m < lane; ++m)
        if (mem[m] == u) uniq = false;
    }
    const unsigned long long bal = __ballot(uniq);
    if (lane == 0) ufm[g] = (unsigned int)bal;
    if (uniq) {
      const int u = mem[lane];
      const int pos = atomicAdd(&deg[u], 1);
      if (pos < CAP) inv[(long)u * CAP + pos] = g;
    }
  }
  // group->samples index
  const int nthreads = gridDim.x * TPB;
  for (int s = blockIdx.x * TPB + threadIdx.x; s < B; s += nthreads) {
    const int gg = groups[s];
    const int pos = atomicAdd(&scnt[gg], 1);
    if (pos < CAPS) sidx[gg * CAPS + pos] = s;
  }
}

// Shared body: updated, l2-normalized embedding of group g. All LDS arrays
// are wave-private -> no block barriers. ng via inverse-index gather, 8 rows
// in flight (2x unrolled float4 4-row loads); pad rows = g, folded into the
// -(ucnt+padc)*e term. nm computed at k==0, reread after.
__device__ __forceinline__ float update_core(
    const int* __restrict__ membership, const unsigned int* __restrict__ ufm,
    const int* __restrict__ deg, const int* __restrict__ inv,
    const float* __restrict__ user_emb, float* __restrict__ nm, int compute_nm,
    const float* __restrict__ Wk, const float* __restrict__ bk, int k,
    const float* __restrict__ cur, int g, int lane,
    int* mem, float* coef, float* e_sh, float* ms_sh, int* nbr) {
  const int sub = lane >> 4, q = lane & 15;
  if (lane < MAXM) mem[lane] = membership[g * MAXM + lane];
  const unsigned int um = ufm[g];
  const float ein = cur[(long)g * D + lane];
  e_sh[lane] = ein;

  int d = 0, u = 0;
  const bool uq = (lane < MAXM) && ((um >> lane) & 1u);
  if (uq) { u = mem[lane]; d = deg[u]; }
  if (lane < MAXM) coef[lane] = uq ? (float)(d - 1) : 0.f;
  const int dc = d < CAP ? d : CAP;
  int incl = dc;
#pragma unroll
  for (int off = 1; off < 64; off <<= 1) {
    const int v = __shfl_up(incl, off);
    if (lane >= off) incl += v;
  }
  const int total = __shfl(incl, 63);
  const int base = incl - dc;
  for (int i = 0; i < dc; ++i) nbr[base + i] = inv[(long)u * CAP + i];
  const int padc = (8 - (total & 7)) & 7;
  if (lane < padc) nbr[total + lane] = g;   // pad rows: subtracted via alpha

  const int T8 = total + padc;
  float4 a0 = make_float4(0.f, 0.f, 0.f, 0.f);
  float4 a1 = make_float4(0.f, 0.f, 0.f, 0.f);
  for (int i = 0; i < T8; i += 8) {
    const int r0 = nbr[i + sub];
    const int r1 = nbr[i + 4 + sub];
    const float4 v0 = *(const float4*)(cur + (long)r0 * D + q * 4);
    const float4 v1 = *(const float4*)(cur + (long)r1 * D + q * 4);
    a0.x += v0.x; a0.y += v0.y; a0.z += v0.z; a0.w += v0.w;
    a1.x += v1.x; a1.y += v1.y; a1.z += v1.z; a1.w += v1.w;
  }
  float4 ng4 = make_float4(a0.x + a1.x, a0.y + a1.y, a0.z + a1.z, a0.w + a1.w);
  XOR_COMBINE4(ng4);

  float4 nm4 = make_float4(0.f, 0.f, 0.f, 0.f);
  if (compute_nm) {
#pragma unroll
    for (int it = 0; it < MAXM / 4; ++it) {
      const int m = it * 4 + sub;
      const float c = coef[m];
      const float4 v = *(const float4*)(user_emb + (long)mem[m] * D + q * 4);
      nm4.x += c * v.x; nm4.y += c * v.y; nm4.z += c * v.z; nm4.w += c * v.w;
    }
    XOR_COMBINE4(nm4);
    if (lane < 16) ((float4*)(nm + (long)g * D))[q] = nm4;
  }
  if (lane < 16) {
    const float4 nmv4 =
        compute_nm ? nm4 : ((const float4*)(nm + (long)g * D))[q];
    const float alpha = (float)__popc(um) + (float)padc;
    const float4 e4 = ((const float4*)e_sh)[q];
    float4 ms4;
    ms4.x = ng4.x + nmv4.x - alpha * e4.x;
    ms4.y = ng4.y + nmv4.y - alpha * e4.y;
    ms4.z = ng4.z + nmv4.z - alpha * e4.z;
    ms4.w = ng4.w + nmv4.w - alpha * e4.w;
    ((float4*)ms_sh)[q] = ms4;
  }

  const float4* W4 = (const float4*)(Wk + ((long)k * D + lane) * (2 * D));
  const float4* e4p = (const float4*)e_sh;
  const float4* m4p = (const float4*)ms_sh;
  float o = bk[k * D + lane];
#pragma unroll
  for (int j = 0; j < 16; ++j) {
    const float4 a = e4p[j], wv = W4[j];
    o += a.x * wv.x + a.y * wv.y + a.z * wv.z + a.w * wv.w;
  }
#pragma unroll
  for (int j = 0; j < 16; ++j) {
    const float4 a = m4p[j], wv = W4[16 + j];
    o += a.x * wv.x + a.y * wv.y + a.z * wv.z + a.w * wv.w;
  }
  float ss = o * o;
#pragma unroll
  for (int sh = 32; sh; sh >>= 1) ss += __shfl_xor(ss, sh);
  return o * (1.f / fmaxf(sqrtf(ss), 1e-12f));
}

// Middle iteration: writes updated embedding.
__global__ __launch_bounds__(TPB) void upd_kernel(
    const int* __restrict__ membership, const unsigned int* __restrict__ ufm,
    const int* __restrict__ deg, const int* __restrict__ inv,
    const float* __restrict__ user_emb, float* __restrict__ nm, int compute_nm,
    const float* __restrict__ Wk, const float* __restrict__ bk, int k,
    const float* __restrict__ cur, float* __restrict__ nxt, int G) {
  const int w = threadIdx.x >> 6, lane = threadIdx.x & 63;
  const int g0 = blockIdx.x * WPB + w;
  const int g = g0 < G ? g0 : G - 1;
  __shared__ int   mem_s[WPB][MAXM];
  __shared__ float coef_s[WPB][MAXM];
  __shared__ float e_s[WPB][D], ms_s[WPB][D];
  __shared__ int   nbr_s[WPB][MAXM * CAP + 8];
  const float o = update_core(membership, ufm, deg, inv, user_emb, nm,
                              compute_nm, Wk, bk, k, cur, g, lane,
                              mem_s[w], coef_s[w], e_s[w], ms_s[w], nbr_s[w]);
  if (g0 < G) nxt[(long)g0 * D + lane] = o;
}

// Last iteration fused with the prediction head; the block's waves pool
// their groups' samples to cut straggler tails.
__global__ __launch_bounds__(TPB) void upd_head_kernel(
    const int* __restrict__ membership, const unsigned int* __restrict__ ufm,
    const int* __restrict__ deg, const int* __restrict__ inv,
    const float* __restrict__ user_emb, float* __restrict__ nm, int compute_nm,
    const float* __restrict__ Wk, const float* __restrict__ bk, int k,
    const float* __restrict__ cur,
    const int* __restrict__ scnt, const int* __restrict__ sidx,
    const int* __restrict__ items, const float* __restrict__ item_emb,
    const float* __restrict__ p1w, const float* __restrict__ p1b,
    const float* __restrict__ p2w, const float* __restrict__ p2b,
    float* __restrict__ out, int G) {
  const int w = threadIdx.x >> 6, lane = threadIdx.x & 63;
  const int g0 = blockIdx.x * WPB + w;
  const int g = g0 < G ? g0 : G - 1;
  __shared__ int   mem_s[WPB][MAXM];
  __shared__ float coef_s[WPB][MAXM];
  __shared__ float e_s[WPB][D], ms_s[WPB][D];
  __shared__ int   nbr_s[WPB][MAXM * CAP + 8];
  const float o = update_core(membership, ufm, deg, inv, user_emb, nm,
                              compute_nm, Wk, bk, k, cur, g, lane,
                              mem_s[w], coef_s[w], e_s[w], ms_s[w], nbr_s[w]);

  __shared__ float o_sh[WPB][D];
  __shared__ int   slist[WPB * CAPS];
  __shared__ unsigned char sgw[WPB * CAPS];
  __shared__ int   soff[WPB + 1];
  __shared__ int   scnt_sh[WPB];
  o_sh[w][lane] = o;
  if (lane == 0) scnt_sh[w] = (g0 < G) ? min(scnt[g0], CAPS) : 0;
  __syncthreads();
  if (threadIdx.x == 0) {
    soff[0] = 0;
    for (int i = 0; i < WPB; ++i) soff[i + 1] = soff[i] + scnt_sh[i];
  }
  __syncthreads();
  const int my = scnt_sh[w];
  for (int i = lane; i < my; i += 64) {
    slist[soff[w] + i] = sidx[g0 * CAPS + i];
    sgw[soff[w] + i] = (unsigned char)w;
  }
  __syncthreads();
  const int T = soff[WPB];
  if (T == 0) return;
  float p1r[16], p1br[16], p2wr[16];
#pragma unroll
  for (int j = 0; j < 16; ++j) {
    p1r[j]  = p1w[j * D + lane];
    p1br[j] = p1b[j];
    p2wr[j] = p2w[j];
  }
  const float p2b0 = p2b[0];
  for (int e = w; e < T; e += WPB) {
    const int s = slist[e];
    const int gw2 = sgw[e];
    const float x = o_sh[gw2][lane] * item_emb[(long)items[s] * D + lane];
    float pv[16];
#pragma unroll
    for (int j = 0; j < 16; ++j) pv[j] = x * p1r[j];
#pragma unroll
    for (int off = 32; off; off >>= 1) {
#pragma unroll
      for (int j = 0; j < 16; ++j) pv[j] += __shfl_xor(pv[j], off);
    }
    float acc2 = p2b0;
#pragma unroll
    for (int j = 0; j < 16; ++j)
      acc2 += fmaxf(pv[j] + p1br[j], 0.f) * p2wr[j];
    if (lane == 0) out[s] = 1.f / (1.f + expf(-acc2));
  }
}

extern "C" void kernel_launch(void* const* d_in, const int* in_sizes, int n_in,
                              void* d_out, int out_size, void* d_ws, size_t ws_size,
                              hipStream_t stream) {
  const int*   groups      = (const int*)d_in[0];
  const int*   items       = (const int*)d_in[1];
  const int*   membership  = (const int*)d_in[2];
  const float* member_mask = (const float*)d_in[3];
  // d_in[4] hyper_graph: not needed (binary incidence == membership lists)
  const float* user_emb    = (const float*)d_in[5];
  const float* item_emb    = (const float*)d_in[6];
  const float* Wk          = (const float*)d_in[7];
  const float* bk          = (const float*)d_in[8];
  const float* p1w         = (const float*)d_in[9];
  const float* p1b         = (const float*)d_in[10];
  const float* p2w         = (const float*)d_in[11];
  const float* p2b         = (const float*)d_in[12];
  float* out = (float*)d_out;

  const int B  = in_sizes[0];
  const int G  = in_sizes[2] / MAXM;
  const int NU = in_sizes[5] / D;
  const int K  = in_sizes[7] / (D * 2 * D);

  char* ws = (char*)d_ws;
  float*        emb_a = (float*)ws;        ws += (size_t)G * D * 4;
  float*        emb_b = (float*)ws;        ws += (size_t)G * D * 4;
  float*        nm    = (float*)ws;        ws += (size_t)G * D * 4;
  int*          deg   = (int*)ws;          ws += (size_t)NU * 4;   // contiguous
  int*          scnt  = (int*)ws;          ws += (size_t)G * 4;    // with deg
  int*          inv   = (int*)ws;          ws += (size_t)NU * CAP * 4;
  int*          sidx  = (int*)ws;          ws += (size_t)G * CAPS * 4;
  unsigned int* ufm   = (unsigned int*)ws; ws += (size_t)G * 4;

  const int nblk = (G + WPB - 1) / WPB;   // 250 blocks: one per CU, uniform

  hipMemsetAsync(deg, 0, (size_t)(NU + G) * 4, stream);  // deg + scnt
  init_kernel<<<nblk, TPB, 0, stream>>>(membership, member_mask, user_emb,
                                        groups, emb_a, ufm, deg, inv,
                                        scnt, sidx, G, B);

  float* cur = emb_a;
  float* nxt = emb_b;
  for (int k = 0; k < K - 1; ++k) {
    upd_kernel<<<nblk, TPB, 0, stream>>>(membership, ufm, deg, inv, user_emb,
                                         nm, (k == 0) ? 1 : 0, Wk, bk, k,
                                         cur, nxt, G);
    float* tmp = cur; cur = nxt; nxt = tmp;
  }
  upd_head_kernel<<<nblk, TPB, 0, stream>>>(
      membership, ufm, deg, inv, user_emb, nm, (K == 1) ? 1 : 0, Wk, bk, K - 1,
      cur, scnt, sidx, items, item_emb, p1w, p1b, p2w, p2b, out, G);
}